// Round 7
// baseline (427.382 us; speedup 1.0000x reference)
//
#include <hip/hip_runtime.h>
#include <float.h>
#include <stdint.h>

// Problem constants
#define Bb   4
#define Nn   2048
#define DIMc 256
#define Hh   8
#define HDd  32
#define Mm   4
#define STOT 2052           // N + M keys
#define ROWS 16             // query rows per attention block (1 per wave)
#define SROW 2112           // full score row: 2048 keys + 4 mem + 60 pad (33*64)
#define NVROW 2052          // extended V rows per batch (N + M)

typedef float f32x2 __attribute__((ext_vector_type(2)));
typedef unsigned long long u64;

// ---------- monotone float <-> sortable uint mapping ----------
__device__ __forceinline__ unsigned int f2key(float s) {
    unsigned int b = __float_as_uint(s);
    return (b & 0x80000000u) ? ~b : (b | 0x80000000u);
}
__device__ __forceinline__ float key2f(unsigned int u) {
    unsigned int b = (u & 0x80000000u) ? (u ^ 0x80000000u) : ~u;
    return __uint_as_float(b);
}

// ---------- QKV GEMM: 128x128 tile, 8x8/thread, dbuf ----------
// Q row-major; K transposed into kT; V extended (mem rows appended).
__global__ __launch_bounds__(256) void sgemm_qkv(
    const float* __restrict__ A, const float* __restrict__ Bm,
    const float* __restrict__ bias, float* __restrict__ Qb,
    float* __restrict__ kTb, float* __restrict__ Vx,
    const float* __restrict__ memv)
{
    __shared__ __align__(16) union {
        struct { float As[2][16][128]; float Bs[2][16][128]; } st;   // 32.8 KB
        float Ts[128][133];                                          // 68.1 KB
    } u;
    const int tid = threadIdx.x;
    const int tx = tid & 15, ty = tid >> 4;
    const int m0 = blockIdx.y * 128, n0 = blockIdx.x * 128;   // n0 in {0..640}
    const int arow = tid >> 1, acol = (tid & 1) * 8;          // A: 2 thr/row
    const int bcol = tx * 8;                                  // B: brow = ty
    float acc[8][8] = {};

    // prologue: stage kb=0 into buffer 0
    {
        const float4 a0 = *(const float4*)&A[(size_t)(m0 + arow) * DIMc + acol];
        const float4 a1 = *(const float4*)&A[(size_t)(m0 + arow) * DIMc + acol + 4];
        const float4 b0 = *(const float4*)&Bm[(size_t)ty * 768 + n0 + bcol];
        const float4 b1 = *(const float4*)&Bm[(size_t)ty * 768 + n0 + bcol + 4];
        const float av[8] = {a0.x,a0.y,a0.z,a0.w,a1.x,a1.y,a1.z,a1.w};
#pragma unroll
        for (int c = 0; c < 8; ++c) u.st.As[0][acol + c][arow] = av[c];
        *(float4*)&u.st.Bs[0][ty][bcol]     = b0;
        *(float4*)&u.st.Bs[0][ty][bcol + 4] = b1;
    }
    int cur = 0;
    for (int kb = 0; kb < DIMc; kb += 16) {
        float4 a0n, a1n, b0n, b1n;
        const bool more = (kb + 16 < DIMc);
        if (more) {
            a0n = *(const float4*)&A[(size_t)(m0 + arow) * DIMc + kb + 16 + acol];
            a1n = *(const float4*)&A[(size_t)(m0 + arow) * DIMc + kb + 16 + acol + 4];
            b0n = *(const float4*)&Bm[(size_t)(kb + 16 + ty) * 768 + n0 + bcol];
            b1n = *(const float4*)&Bm[(size_t)(kb + 16 + ty) * 768 + n0 + bcol + 4];
        }
        __syncthreads();        // buf[cur] staged; prev compute done
#pragma unroll
        for (int k = 0; k < 16; ++k) {
            const float4 av0 = *(const float4*)&u.st.As[cur][k][ty * 8];
            const float4 av1 = *(const float4*)&u.st.As[cur][k][ty * 8 + 4];
            const float4 bv0 = *(const float4*)&u.st.Bs[cur][k][tx * 8];
            const float4 bv1 = *(const float4*)&u.st.Bs[cur][k][tx * 8 + 4];
            const float aa[8] = {av0.x,av0.y,av0.z,av0.w,av1.x,av1.y,av1.z,av1.w};
            const float bb[8] = {bv0.x,bv0.y,bv0.z,bv0.w,bv1.x,bv1.y,bv1.z,bv1.w};
#pragma unroll
            for (int i = 0; i < 8; ++i)
#pragma unroll
                for (int j = 0; j < 8; ++j)
                    acc[i][j] = fmaf(aa[i], bb[j], acc[i][j]);
        }
        if (more) {
            const float av[8] = {a0n.x,a0n.y,a0n.z,a0n.w,a1n.x,a1n.y,a1n.z,a1n.w};
#pragma unroll
            for (int c = 0; c < 8; ++c) u.st.As[cur ^ 1][acol + c][arow] = av[c];
            *(float4*)&u.st.Bs[cur ^ 1][ty][bcol]     = b0n;
            *(float4*)&u.st.Bs[cur ^ 1][ty][bcol + 4] = b1n;
        }
        cur ^= 1;
    }
    const float4 bv0 = *(const float4*)&bias[n0 + tx * 8];
    const float4 bv1 = *(const float4*)&bias[n0 + tx * 8 + 4];
    const float bb[8] = {bv0.x,bv0.y,bv0.z,bv0.w,bv1.x,bv1.y,bv1.z,bv1.w};
    const int path = n0 >> 8;                          // 0=Q, 1=K, 2=V
    if (path == 1) {
        // K: row-major tile into Ts (union overlaps staging -> barrier first)
        __syncthreads();
#pragma unroll
        for (int i = 0; i < 8; ++i) {
            float4 o0, o1;
            o0.x = acc[i][0] + bb[0]; o0.y = acc[i][1] + bb[1];
            o0.z = acc[i][2] + bb[2]; o0.w = acc[i][3] + bb[3];
            o1.x = acc[i][4] + bb[4]; o1.y = acc[i][5] + bb[5];
            o1.z = acc[i][6] + bb[6]; o1.w = acc[i][7] + bb[7];
            *(float4*)&u.Ts[ty * 8 + i][tx * 8]     = o0;
            *(float4*)&u.Ts[ty * 8 + i][tx * 8 + 4] = o1;
        }
        __syncthreads();
        // scatter columns of Ts into dense kT rows
        const int c_local = tid >> 1, seg = tid & 1;
        const int cg = (n0 - 256) + c_local;           // 0..255
        const int hh = cg >> 5, dd = cg & 31;
        const int bi = m0 >> 11, j0 = (m0 & 2047) + seg * 64;
        float* dst = kTb + (((size_t)(bi * Hh + hh) * HDd + dd) * Nn) + j0;
#pragma unroll
        for (int q = 0; q < 16; ++q) {
            float4 o;
            o.x = u.Ts[seg * 64 + q * 4 + 0][c_local];
            o.y = u.Ts[seg * 64 + q * 4 + 1][c_local];
            o.z = u.Ts[seg * 64 + q * 4 + 2][c_local];
            o.w = u.Ts[seg * 64 + q * 4 + 3][c_local];
            *(float4*)(dst + q * 4) = o;
        }
    } else if (path == 0) {
        const int c0 = n0 + tx * 8;                    // Q columns 0..255
#pragma unroll
        for (int i = 0; i < 8; ++i) {
            float4 o0, o1;
            o0.x = acc[i][0] + bb[0]; o0.y = acc[i][1] + bb[1];
            o0.z = acc[i][2] + bb[2]; o0.w = acc[i][3] + bb[3];
            o1.x = acc[i][4] + bb[4]; o1.y = acc[i][5] + bb[5];
            o1.z = acc[i][6] + bb[6]; o1.w = acc[i][7] + bb[7];
            float* dst = &Qb[(size_t)(m0 + ty * 8 + i) * 256 + c0];
            *(float4*)dst = o0; *(float4*)(dst + 4) = o1;
        }
    } else {
        // V: store into extended layout [b][2052][256]
        const int c0 = (n0 & 255) + tx * 8;
        const size_t row_base = (size_t)(m0 >> 11) * NVROW + (m0 & 2047);
#pragma unroll
        for (int i = 0; i < 8; ++i) {
            float4 o0, o1;
            o0.x = acc[i][0] + bb[0]; o0.y = acc[i][1] + bb[1];
            o0.z = acc[i][2] + bb[2]; o0.w = acc[i][3] + bb[3];
            o1.x = acc[i][4] + bb[4]; o1.y = acc[i][5] + bb[5];
            o1.z = acc[i][6] + bb[6]; o1.w = acc[i][7] + bb[7];
            float* dst = &Vx[(row_base + ty * 8 + i) * 256 + c0];
            *(float4*)dst = o0; *(float4*)(dst + 4) = o1;
        }
        // 4 designated blocks (one per batch) append the 4 mem_v rows
        if (n0 == 512 && (m0 & 2047) == 0) {
            const int bb2 = m0 >> 11;
#pragma unroll
            for (int mm = 0; mm < Mm; ++mm)
                Vx[((size_t)bb2 * NVROW + Nn + mm) * 256 + tid] =
                    memv[((tid >> 5) * Mm + mm) * HDd + (tid & 31)];
        }
    }
}

// ---------- final projection: 128x64 tiles, 8x4/thread, dbuf ----------
__global__ __launch_bounds__(256) void sgemm_bias(
    const float* __restrict__ A, const float* __restrict__ Bm,
    const float* __restrict__ bias, float* __restrict__ C,
    int Md, int Nd, int Kd)
{
    __shared__ __align__(16) float As[2][16][128];
    __shared__ __align__(16) float Bs[2][16][64];
    const int tid = threadIdx.x;
    const int tx = tid & 15, ty = tid >> 4;
    const int m0 = blockIdx.y * 128, n0 = blockIdx.x * 64;
    const int arow = tid >> 1, acol = (tid & 1) * 8;
    const int brow = tid >> 4, bcol = (tid & 15) * 4;
    float acc[8][4] = {};

    {
        const float4 a0 = *(const float4*)&A[(size_t)(m0 + arow) * Kd + acol];
        const float4 a1 = *(const float4*)&A[(size_t)(m0 + arow) * Kd + acol + 4];
        const float4 b0 = *(const float4*)&Bm[(size_t)brow * Nd + n0 + bcol];
        const float av[8] = {a0.x,a0.y,a0.z,a0.w,a1.x,a1.y,a1.z,a1.w};
#pragma unroll
        for (int c = 0; c < 8; ++c) As[0][acol + c][arow] = av[c];
        *(float4*)&Bs[0][brow][bcol] = b0;
    }
    int cur = 0;
    for (int kb = 0; kb < Kd; kb += 16) {
        float4 a0n, a1n, b0n;
        const bool more = (kb + 16 < Kd);
        if (more) {
            a0n = *(const float4*)&A[(size_t)(m0 + arow) * Kd + kb + 16 + acol];
            a1n = *(const float4*)&A[(size_t)(m0 + arow) * Kd + kb + 16 + acol + 4];
            b0n = *(const float4*)&Bm[(size_t)(kb + 16 + brow) * Nd + n0 + bcol];
        }
        __syncthreads();
#pragma unroll
        for (int k = 0; k < 16; ++k) {
            const float4 av0 = *(const float4*)&As[cur][k][ty * 8];
            const float4 av1 = *(const float4*)&As[cur][k][ty * 8 + 4];
            const float4 bq  = *(const float4*)&Bs[cur][k][tx * 4];
            const float aa[8] = {av0.x,av0.y,av0.z,av0.w,av1.x,av1.y,av1.z,av1.w};
            const float bb[4] = {bq.x, bq.y, bq.z, bq.w};
#pragma unroll
            for (int i = 0; i < 8; ++i)
#pragma unroll
                for (int j = 0; j < 4; ++j)
                    acc[i][j] = fmaf(aa[i], bb[j], acc[i][j]);
        }
        if (more) {
            const float av[8] = {a0n.x,a0n.y,a0n.z,a0n.w,a1n.x,a1n.y,a1n.z,a1n.w};
#pragma unroll
            for (int c = 0; c < 8; ++c) As[cur ^ 1][acol + c][arow] = av[c];
            *(float4*)&Bs[cur ^ 1][brow][bcol] = b0n;
        }
        cur ^= 1;
    }
    const float4 bv = *(const float4*)&bias[n0 + tx * 4];
    const float bb[4] = {bv.x, bv.y, bv.z, bv.w};
#pragma unroll
    for (int i = 0; i < 8; ++i) {
        float4 o;
        o.x = acc[i][0] + bb[0];
        o.y = acc[i][1] + bb[1];
        o.z = acc[i][2] + bb[2];
        o.w = acc[i][3] + bb[3];
        *(float4*)&C[(size_t)(m0 + ty * 8 + i) * Nd + n0 + tx * 4] = o;
    }
}

// packed-pair fma step over 2 keys: a2 += {q,q} * kd[P]
// Per-key chain identical to prior rounds -> bit-identical scores.
#if __has_builtin(__builtin_elementwise_fma)
#define PK2(Q, P)                                                           \
    { const f32x2 qq = {(Q), (Q)};                                          \
      a2 = __builtin_elementwise_fma(qq, kd[P], a2); }
#else
#define PK2(Q, P)                                                           \
    { a2.x = fmaf((Q), kd[P].x, a2.x); a2.y = fmaf((Q), kd[P].y, a2.y); }
#endif

// pipelined score helpers (2 keys/thread): next-dc loads issue before this
// dc's FMA. q read from GLOBAL (wave-uniform -> scalar path).
#define SCORE_LD(KD, DC)                                                    \
    _Pragma("unroll")                                                       \
    for (int dd = 0; dd < 8; ++dd)                                          \
        KD[dd] = *(const f32x2*)&kT[((DC) * 8 + dd) * Nn + j0];

#define SCORE_FMA(KD, DC)                                                   \
    _Pragma("unroll")                                                       \
    for (int r = 0; r < ROWS; ++r) {                                        \
        const float4 qa  = *(const float4*)&qrow[r * 256 + (DC) * 8];       \
        const float4 qb2 = *(const float4*)&qrow[r * 256 + (DC) * 8 + 4];   \
        const f32x2* kd = KD;                                               \
        f32x2 a2 = accp[r];                                                 \
        PK2(qa.x, 0) PK2(qa.y, 1) PK2(qa.z, 2) PK2(qa.w, 3)                 \
        PK2(qb2.x, 4) PK2(qb2.y, 5) PK2(qb2.z, 6) PK2(qb2.w, 7)             \
        accp[r] = a2;                                                       \
    }

// ---------- sparse top-32 attention (R18: ROWS=16, halved kT stream) ----------
__global__ __launch_bounds__(1024, 4) void attn_sparse(
    const float* __restrict__ Qb, const float* __restrict__ kTb,
    const float* __restrict__ Vx, const float* __restrict__ memk,
    const float* __restrict__ scale, float* __restrict__ attn_out)
{
    __shared__ __align__(16) unsigned int S[ROWS][SROW];   // sortable keys, 132 KB
    __shared__ __align__(16) u64 ulist64[ROWS][64];        // 8 KB  (u<<32 | j)
    __shared__ __align__(16) u64 wj_list[ROWS][64];        // 8 KB  (j<<32 | w bits)

    const int tid    = threadIdx.x;                   // 0..1023
    const int ntiles = Nn / ROWS;                     // 128
    const int tile   = blockIdx.x % ntiles;
    const int h      = (blockIdx.x / ntiles) % Hh;
    const int b      = blockIdx.x / (ntiles * Hh);
    const int n0     = tile * ROWS;
    const float sc   = scale[h] * 0.17677669529663688f;

    // wave-uniform q base: q reads go through the scalar path, not LDS
    const float* qrow = Qb + (size_t)(b * Nn + n0) * 256 + h * HDd;
    const float* kT = kTb + (size_t)(b * Hh + h) * (HDd * Nn);   // [32][2048]

    // ---- score phase: keys 0..2047, 1024 threads x 2 keys, 2-deep pipeline ----
    {
        const int j0 = tid * 2;
        f32x2 accp[ROWS];
#pragma unroll
        for (int r = 0; r < ROWS; ++r) accp[r] = (f32x2){0.f, 0.f};
        f32x2 kdA[8], kdB[8];
        SCORE_LD(kdA, 0)
        SCORE_LD(kdB, 1)
        SCORE_FMA(kdA, 0)
        SCORE_LD(kdA, 2)
        SCORE_FMA(kdB, 1)
        SCORE_LD(kdB, 3)
        SCORE_FMA(kdA, 2)
        SCORE_FMA(kdB, 3)
#pragma unroll
        for (int r = 0; r < ROWS; ++r) {
            uint2 o;
            float s0 = accp[r].x * sc;
            float s1 = accp[r].y * sc;
            if (j0 + 0 == n0 + r) s0 = -FLT_MAX;      // diag mask
            if (j0 + 1 == n0 + r) s1 = -FLT_MAX;
            o.x = f2key(s0);
            o.y = f2key(s1);
            *(uint2*)&S[r][j0] = o;
        }
    }
    // ---- mem keys 2048..2051: 64 threads (row r, key m), d ascending chain ----
    if (tid < 64) {
        const int r = tid >> 2, m = tid & 3;
        const float* kp = memk + (size_t)(h * Mm + m) * HDd;
        float acc = 0.f;
#pragma unroll
        for (int dcc = 0; dcc < 8; ++dcc) {
            const float4 qv = *(const float4*)&qrow[r * 256 + dcc * 4];
            const float4 kv = *(const float4*)&kp[dcc * 4];
            acc = fmaf(qv.x, kv.x, acc);
            acc = fmaf(qv.y, kv.y, acc);
            acc = fmaf(qv.z, kv.z, acc);
            acc = fmaf(qv.w, kv.w, acc);
        }
        S[r][2048 + m] = f2key(acc * sc);
    } else {
        // pads 2052..2111: 16 rows x 60 slots = 960 writes by threads 64..1023
        const int t2 = tid - 64;
        const int r = t2 / 60, p = t2 % 60;
        S[r][2052 + p] = 0x00800000u;   // f2key(-FLT_MAX)
    }
    __syncthreads();

    // ---- phase 2: one row per wave; keys cached in registers ----
    const int wave = tid >> 6, lane = tid & 63;
    const int half = lane >> 5, d = lane & 31;
    const int n = n0 + wave;

    unsigned int uv[33];
    unsigned int mx = 0u;
    {
        const unsigned int* Srow = &S[wave][lane];
#pragma unroll
        for (int i = 0; i < 33; ++i) {
            uv[i] = Srow[i * 64];
            mx = uv[i] > mx ? uv[i] : mx;
        }
    }
    // slot (i, lane) holds key index j = i*64 + lane.

    auto bitonic = [&](unsigned int vv) -> unsigned int {
#pragma unroll
        for (int kk = 2; kk <= 64; kk <<= 1)
#pragma unroll
            for (int jj = kk >> 1; jj > 0; jj >>= 1) {
                const unsigned int o = (unsigned int)__shfl_xor((int)vv, jj);
                const unsigned int mn = vv < o ? vv : o;
                const unsigned int mxv = vv < o ? o : vv;
                const bool up   = ((lane & kk) == 0);
                const bool lowr = ((lane & jj) == 0);
                vv = (lowr == up) ? mn : mxv;
            }
        return vv;   // ascending: lane 63 = max, lane 32 = 32nd largest
    };
    auto countge = [&](unsigned int tt) -> int {
        int gg = 0;
#pragma unroll
        for (int i = 0; i < 33; ++i) gg += (int)__popcll(__ballot(uv[i] >= tt));
        return gg;   // wave-uniform
    };
    auto compact = [&](unsigned int tt) -> int {
        int bs = 0;
#pragma unroll
        for (int i = 0; i < 33; ++i) {
            const bool p = (uv[i] >= tt);
            const unsigned long long mk = __ballot(p);
            if (p) {
                const int pos = bs + (int)__popcll(mk & ((1ull << lane) - 1ull));
                if (pos < 64)
                    ulist64[wave][pos] = ((u64)uv[i] << 32) | (unsigned int)(i * 64 + lane);
            }
            bs += (int)__popcll(mk);
        }
        return bs;   // wave-uniform total count(>= tt)
    };

    // threshold from lane-max sort: L32 = 32nd-largest lane-max.
    const unsigned int vs1 = bitonic(mx);
    const unsigned int Lmax = (unsigned int)__shfl((int)vs1, 63);   // global max key
    unsigned int t = (unsigned int)__shfl((int)vs1, 32);

    // compact immediately; base IS count(>=t)
    ulist64[wave][lane] = 0ull;
    __asm__ __volatile__("s_waitcnt lgkmcnt(0)" ::: "memory");
    int base = compact(t);
    bool exact = true;
    if (base > 64) {                   // rare: refine with uint bisection
        unsigned int blo = t, bhi = Lmax + 1;   // count(>=blo)>64, count(>=bhi)==0
        int found = 0;
#pragma unroll 1
        for (int it = 0; it < 33; ++it) {
            if (bhi - blo <= 1u) break;
            const unsigned int tm = blo + ((bhi - blo) >> 1);
            const int gm = countge(tm);
            if (gm > 64) blo = tm;
            else if (gm < 32) bhi = tm;
            else { t = tm; found = 1; break; }
        }
        if (!found) t = blo;
        ulist64[wave][lane] = 0ull;
        __asm__ __volatile__("s_waitcnt lgkmcnt(0)" ::: "memory");
        base = compact(t);
        exact = (base <= 64);
    }
    const int C2 = base < 64 ? base : 64;
    __asm__ __volatile__("s_waitcnt lgkmcnt(0)" ::: "memory");
    const u64 pk = ulist64[wave][lane];
    const unsigned int ue = (unsigned int)(pk >> 32);
    const int je = (int)(unsigned int)pk;

    // exact 32nd largest from candidate sort (zeros pad the bottom)
    const unsigned int vs2 = bitonic(ue);
    unsigned int vkkey = (unsigned int)__shfl((int)vs2, 32);
    const unsigned int v31u = (unsigned int)__shfl((int)vs2, 31);
    if (!exact) vkkey = t;

    // ---- boundary analysis from sort byproducts ----
    const bool tie_span = (v31u == vkkey);       // 33rd largest == vk  <=> ties span
    float snx = -3.0e38f;
    if (exact && !tie_span) {
        if (C2 == 32) {       // 33rd largest not in candidate set: sweep for it
            unsigned int unx = 0u;
#pragma unroll
            for (int i = 0; i < 33; ++i) {
                const unsigned int u = uv[i];
                if (u < vkkey && u > unx) unx = u;
            }
#pragma unroll
            for (int o = 32; o > 0; o >>= 1) {
                const unsigned int ou = (unsigned int)__shfl_xor((int)unx, o);
                if (ou > unx) unx = ou;
            }
            snx = key2f(unx);
        } else {
            snx = key2f(v31u);                   // 33rd largest, < vk
        }
    }
    const float svk  = key2f(vkkey);
    const float gapv = svk - snx;
    const float lam  = (exact && !tie_span && gapv > 0.f && gapv <= 4.0e-6f) ? 0.13f : 0.f;

    // softmax weights over kept entries (u >= vkkey); prefilled tail has u=0 -> w=0
    const float mval = key2f(Lmax);
    const float we = (ue >= vkkey) ? __expf(key2f(ue) - mval) : 0.f;
    // half-split layout: evens at 0..31, odds at 32..63
    wj_list[wave][(lane & 1) * 32 + (lane >> 1)] =
        ((u64)(unsigned int)je << 32) | (u64)__float_as_uint(we);
    float Z = we;
#pragma unroll
    for (int o = 32; o > 0; o >>= 1) Z += __shfl_xor(Z, o);
    __asm__ __volatile__("s_waitcnt lgkmcnt(0)" ::: "memory");

    // sparse PV: 8 entries per group; half0 even entries, half1 odd. fma order
    // is program order (e ascending) -> bit-identical; loads pipeline across
    // groups (unroll 2) with 32-bit offsets off a uniform base.
    const float* Vbh = Vx + (size_t)b * (NVROW * 256) + h * HDd;
    float outv = 0.f;
#pragma unroll 2
    for (int e0 = 0; e0 < C2; e0 += 8) {
        const int p0 = (e0 >> 1) + half * 32;
        const ulonglong2 wa = *(const ulonglong2*)&wj_list[wave][p0];
        const ulonglong2 wb = *(const ulonglong2*)&wj_list[wave][p0 + 2];
        float w[4]; unsigned int q[4];
        w[0] = __uint_as_float((unsigned int)wa.x); q[0] = (unsigned int)(wa.x >> 32);
        w[1] = __uint_as_float((unsigned int)wa.y); q[1] = (unsigned int)(wa.y >> 32);
        w[2] = __uint_as_float((unsigned int)wb.x); q[2] = (unsigned int)(wb.x >> 32);
        w[3] = __uint_as_float((unsigned int)wb.y); q[3] = (unsigned int)(wb.y >> 32);
        float vv[4];
#pragma unroll
        for (int u2 = 0; u2 < 4; ++u2)
            vv[u2] = Vbh[q[u2] * 256u + (unsigned int)d];
#pragma unroll
        for (int u2 = 0; u2 < 4; ++u2)
            outv = fmaf(w[u2], vv[u2], outv);
    }
    outv += __shfl_xor(outv, 32);

    float res = outv / Z;
    if (lam > 0.f) {
        // rare hedge: recover indices jd1 (lowest kept) / jnx (highest dropped)
        unsigned int unx2 = 0u; int jnx = 0, jd1 = -1;
#pragma unroll
        for (int i = 0; i < 33; ++i) {
            const unsigned int u = uv[i];
            const int jj2 = i * 64 + lane;
            if (u < vkkey && u > unx2) { unx2 = u; jnx = jj2; }
            if (u == vkkey && jj2 > jd1) jd1 = jj2;
        }
#pragma unroll
        for (int o = 32; o > 0; o >>= 1) {
            const unsigned int ou = (unsigned int)__shfl_xor((int)unx2, o);
            const int oj = __shfl_xor(jnx, o);
            if (ou > unx2 || (ou == unx2 && oj > jnx)) { unx2 = ou; jnx = oj; }
            const int od = __shfl_xor(jd1, o);
            if (od > jd1) jd1 = od;
        }
        const float wd = __expf(svk - mval);
        const float wn = __expf(key2f(unx2) - mval);
        const float* vp1 = Vbh + (size_t)jd1 * 256;
        const float* vpn = Vbh + (size_t)jnx * 256;
        const float ZB = Z - wd + wn;
        const float oB = (outv - wd * vp1[d] + wn * vpn[d]) / ZB;
        res = (1.f - lam) * res + lam * oB;
    }
    if (half == 0)
        attn_out[(size_t)(b * Nn + n) * 256 + h * HDd + d] = res;
}

extern "C" void kernel_launch(void* const* d_in, const int* in_sizes, int n_in,
                              void* d_out, int out_size, void* d_ws, size_t ws_size,
                              hipStream_t stream) {
    const float* x      = (const float*)d_in[0];
    const float* w_qkv  = (const float*)d_in[1];
    const float* b_qkv  = (const float*)d_in[2];
    const float* w_proj = (const float*)d_in[3];
    const float* b_proj = (const float*)d_in[4];
    const float* scale  = (const float*)d_in[5];
    const float* mem_k  = (const float*)d_in[6];
    const float* mem_v  = (const float*)d_in[7];
    float* out = (float*)d_out;

    // workspace: Q/aout 8 MB | kT 8 MB | Vext 8.02 MB  (attn output aliases Qb:
    // each attn block reads exactly the Q slots it later writes; all q reads
    // precede the post-score barrier, all output writes follow it -> race-free)
    float* Qb  = (float*)d_ws;
    float* kTb = Qb  + (size_t)Bb * Nn * 256;
    float* Vx  = kTb + (size_t)Bb * Hh * HDd * Nn;

    sgemm_qkv<<<dim3(768 / 128, (Bb * Nn) / 128), 256, 0, stream>>>(
        x, w_qkv, b_qkv, Qb, kTb, Vx, mem_v);

    attn_sparse<<<dim3(Bb * Hh * (Nn / ROWS)), 1024, 0, stream>>>(
        Qb, kTb, Vx, mem_k, scale, Qb);

    sgemm_bias<<<dim3(DIMc / 64, (Bb * Nn) / 128), 256, 0, stream>>>(
        Qb, w_proj, b_proj, out, Bb * Nn, DIMc, DIMc);
}

// Round 8
// 345.311 us; speedup vs baseline: 1.2377x; 1.2377x over previous
//
#include <hip/hip_runtime.h>
#include <float.h>
#include <stdint.h>

// Problem constants
#define Bb   4
#define Nn   2048
#define DIMc 256
#define Hh   8
#define HDd  32
#define Mm   4
#define STOT 2052           // N + M keys
#define ROWS 8              // query rows per attention block (1 per wave)
#define SROW 2112           // full score row: 2048 keys + 4 mem + 60 pad (33*64)
#define NVROW 2052          // extended V rows per batch (N + M)

typedef float f32x2 __attribute__((ext_vector_type(2)));
typedef unsigned long long u64;

// ---------- monotone float <-> sortable uint mapping ----------
__device__ __forceinline__ unsigned int f2key(float s) {
    unsigned int b = __float_as_uint(s);
    return (b & 0x80000000u) ? ~b : (b | 0x80000000u);
}
__device__ __forceinline__ float key2f(unsigned int u) {
    unsigned int b = (u & 0x80000000u) ? (u ^ 0x80000000u) : ~u;
    return __uint_as_float(b);
}

// ---------- QKV GEMM: 128x64 tile, 8x4/thread, dbuf; grid 768 = 3 blocks/CU ----------
// Q row-major; K transposed into kT; V extended (mem rows appended).
__global__ __launch_bounds__(256) void sgemm_qkv(
    const float* __restrict__ A, const float* __restrict__ Bm,
    const float* __restrict__ bias, float* __restrict__ Qb,
    float* __restrict__ kTb, float* __restrict__ Vx,
    const float* __restrict__ memv)
{
    __shared__ __align__(16) union {
        struct { float As[2][16][128]; float Bs[2][16][64]; } st;   // 24 KB
        float Ts[128][65];                                          // 33.3 KB
    } u;
    const int tid = threadIdx.x;
    const int tx = tid & 15, ty = tid >> 4;
    const int m0 = blockIdx.y * 128, n0 = blockIdx.x * 64;   // n0 in [0,768)
    const int arow = tid >> 1, acol = (tid & 1) * 8;         // A: 2 thr/row
    const int brow = tid >> 4, bcol = (tid & 15) * 4;
    float acc[8][4] = {};

    // prologue: stage kb=0 into buffer 0
    {
        const float4 a0 = *(const float4*)&A[(size_t)(m0 + arow) * DIMc + acol];
        const float4 a1 = *(const float4*)&A[(size_t)(m0 + arow) * DIMc + acol + 4];
        const float4 b0 = *(const float4*)&Bm[(size_t)brow * 768 + n0 + bcol];
        const float av[8] = {a0.x,a0.y,a0.z,a0.w,a1.x,a1.y,a1.z,a1.w};
#pragma unroll
        for (int c = 0; c < 8; ++c) u.st.As[0][acol + c][arow] = av[c];
        *(float4*)&u.st.Bs[0][brow][bcol] = b0;
    }
    int cur = 0;
    for (int kb = 0; kb < DIMc; kb += 16) {
        float4 a0n, a1n, b0n;
        const bool more = (kb + 16 < DIMc);
        if (more) {
            a0n = *(const float4*)&A[(size_t)(m0 + arow) * DIMc + kb + 16 + acol];
            a1n = *(const float4*)&A[(size_t)(m0 + arow) * DIMc + kb + 16 + acol + 4];
            b0n = *(const float4*)&Bm[(size_t)(kb + 16 + brow) * 768 + n0 + bcol];
        }
        __syncthreads();        // buf[cur] staged; prev compute done
#pragma unroll
        for (int k = 0; k < 16; ++k) {
            const float4 av0 = *(const float4*)&u.st.As[cur][k][ty * 8];
            const float4 av1 = *(const float4*)&u.st.As[cur][k][ty * 8 + 4];
            const float4 bq  = *(const float4*)&u.st.Bs[cur][k][tx * 4];
            const float aa[8] = {av0.x,av0.y,av0.z,av0.w,av1.x,av1.y,av1.z,av1.w};
            const float bb[4] = {bq.x, bq.y, bq.z, bq.w};
#pragma unroll
            for (int i = 0; i < 8; ++i)
#pragma unroll
                for (int j = 0; j < 4; ++j)
                    acc[i][j] = fmaf(aa[i], bb[j], acc[i][j]);
        }
        if (more) {
            const float av[8] = {a0n.x,a0n.y,a0n.z,a0n.w,a1n.x,a1n.y,a1n.z,a1n.w};
#pragma unroll
            for (int c = 0; c < 8; ++c) u.st.As[cur ^ 1][acol + c][arow] = av[c];
            *(float4*)&u.st.Bs[cur ^ 1][brow][bcol] = b0n;
        }
        cur ^= 1;
    }
    const float4 bv = *(const float4*)&bias[n0 + tx * 4];
    const float bb[4] = {bv.x, bv.y, bv.z, bv.w};
    const int path = n0 >> 8;                          // 0=Q, 1=K, 2=V
    if (path == 1) {
        // K: tile into Ts (union overlaps staging -> barrier first), then
        // scatter columns of Ts into dense kT rows.
        __syncthreads();
#pragma unroll
        for (int i = 0; i < 8; ++i) {
            float4 o;
            o.x = acc[i][0] + bb[0];
            o.y = acc[i][1] + bb[1];
            o.z = acc[i][2] + bb[2];
            o.w = acc[i][3] + bb[3];
            *(float4*)&u.Ts[ty * 8 + i][tx * 4] = o;
        }
        __syncthreads();
        const int c_local = tid >> 2, seg = tid & 3;   // col 0..63, m-seg 0..3
        const int cg = (n0 - 256) + c_local;           // 0..255
        const int hh = cg >> 5, dd = cg & 31;
        const int bi = m0 >> 11, j0 = (m0 & 2047) + seg * 32;
        float* dst = kTb + (((size_t)(bi * Hh + hh) * HDd + dd) * Nn) + j0;
#pragma unroll
        for (int q = 0; q < 8; ++q) {
            float4 o;
            o.x = u.Ts[seg * 32 + q * 4 + 0][c_local];
            o.y = u.Ts[seg * 32 + q * 4 + 1][c_local];
            o.z = u.Ts[seg * 32 + q * 4 + 2][c_local];
            o.w = u.Ts[seg * 32 + q * 4 + 3][c_local];
            *(float4*)(dst + q * 4) = o;
        }
    } else if (path == 0) {
        const int c0 = n0 + tx * 4;                    // Q columns 0..255
#pragma unroll
        for (int i = 0; i < 8; ++i) {
            float4 o;
            o.x = acc[i][0] + bb[0];
            o.y = acc[i][1] + bb[1];
            o.z = acc[i][2] + bb[2];
            o.w = acc[i][3] + bb[3];
            *(float4*)&Qb[(size_t)(m0 + ty * 8 + i) * 256 + c0] = o;
        }
    } else {
        // V: store into extended layout [b][2052][256]
        const int c0 = (n0 & 255) + tx * 4;
        const size_t row_base = (size_t)(m0 >> 11) * NVROW + (m0 & 2047);
#pragma unroll
        for (int i = 0; i < 8; ++i) {
            float4 o;
            o.x = acc[i][0] + bb[0];
            o.y = acc[i][1] + bb[1];
            o.z = acc[i][2] + bb[2];
            o.w = acc[i][3] + bb[3];
            *(float4*)&Vx[(row_base + ty * 8 + i) * 256 + c0] = o;
        }
        // 4 designated blocks (one per batch) append the 4 mem_v rows
        if (n0 == 512 && (m0 & 2047) == 0) {
            const int bb2 = m0 >> 11;
#pragma unroll
            for (int mm = 0; mm < Mm; ++mm)
                Vx[((size_t)bb2 * NVROW + Nn + mm) * 256 + tid] =
                    memv[((tid >> 5) * Mm + mm) * HDd + (tid & 31)];
        }
    }
}

// ---------- final projection: 64x64 tiles, 4x4/thread, dbuf; grid 512 = 2/CU ----------
__global__ __launch_bounds__(256) void sgemm_bias(
    const float* __restrict__ A, const float* __restrict__ Bm,
    const float* __restrict__ bias, float* __restrict__ C,
    int Md, int Nd, int Kd)
{
    __shared__ __align__(16) float As[2][16][68];
    __shared__ __align__(16) float Bs[2][16][64];
    const int tid = threadIdx.x;
    const int tx = tid & 15, ty = tid >> 4;
    const int m0 = blockIdx.y * 64, n0 = blockIdx.x * 64;
    const int arow = tid >> 2, acol = (tid & 3) * 4;
    const int brow = tid >> 4, bcol = (tid & 15) * 4;
    float acc[4][4] = {};

    {
        const float4 av = *(const float4*)&A[(size_t)(m0 + arow) * Kd + acol];
        const float4 b0 = *(const float4*)&Bm[(size_t)brow * Nd + n0 + bcol];
        As[0][acol + 0][arow] = av.x;
        As[0][acol + 1][arow] = av.y;
        As[0][acol + 2][arow] = av.z;
        As[0][acol + 3][arow] = av.w;
        *(float4*)&Bs[0][brow][bcol] = b0;
    }
    int cur = 0;
    for (int kb = 0; kb < Kd; kb += 16) {
        float4 avn, bvn;
        const bool more = (kb + 16 < Kd);
        if (more) {
            avn = *(const float4*)&A[(size_t)(m0 + arow) * Kd + kb + 16 + acol];
            bvn = *(const float4*)&Bm[(size_t)(kb + 16 + brow) * Nd + n0 + bcol];
        }
        __syncthreads();
#pragma unroll
        for (int k = 0; k < 16; ++k) {
            const float4 a  = *(const float4*)&As[cur][k][ty * 4];
            const float4 bq = *(const float4*)&Bs[cur][k][tx * 4];
            const float aa[4] = {a.x, a.y, a.z, a.w};
            const float bb[4] = {bq.x, bq.y, bq.z, bq.w};
#pragma unroll
            for (int i = 0; i < 4; ++i)
#pragma unroll
                for (int j = 0; j < 4; ++j)
                    acc[i][j] = fmaf(aa[i], bb[j], acc[i][j]);
        }
        if (more) {
            As[cur ^ 1][acol + 0][arow] = avn.x;
            As[cur ^ 1][acol + 1][arow] = avn.y;
            As[cur ^ 1][acol + 2][arow] = avn.z;
            As[cur ^ 1][acol + 3][arow] = avn.w;
            *(float4*)&Bs[cur ^ 1][brow][bcol] = bvn;
        }
        cur ^= 1;
    }
    const float4 bv = *(const float4*)&bias[n0 + tx * 4];
    const float bb[4] = {bv.x, bv.y, bv.z, bv.w};
#pragma unroll
    for (int i = 0; i < 4; ++i) {
        float4 o;
        o.x = acc[i][0] + bb[0];
        o.y = acc[i][1] + bb[1];
        o.z = acc[i][2] + bb[2];
        o.w = acc[i][3] + bb[3];
        *(float4*)&C[(size_t)(m0 + ty * 4 + i) * Nd + n0 + tx * 4] = o;
    }
}

// packed-pair fma step: acc01 += q * kd[P].xy ; acc23 += q * kd[P].zw
#if __has_builtin(__builtin_elementwise_fma)
#define PKSTEP(Q, P)                                                        \
    { const f32x2 qq = {(Q), (Q)};                                          \
      a01 = __builtin_elementwise_fma(qq, ((const f32x2*)&kd[P])[0], a01);  \
      a23 = __builtin_elementwise_fma(qq, ((const f32x2*)&kd[P])[1], a23); }
#else
#define PKSTEP(Q, P)                                                        \
    { a01.x = fmaf((Q), kd[P].x, a01.x); a01.y = fmaf((Q), kd[P].y, a01.y); \
      a23.x = fmaf((Q), kd[P].z, a23.x); a23.y = fmaf((Q), kd[P].w, a23.y); }
#endif

// pipelined score helpers: loads for the NEXT dc issue before this dc's FMA.
// FMA chain order per accumulator is unchanged -> bit-identical scores.
#define SCORE_LD(KD, DC)                                                    \
    _Pragma("unroll")                                                       \
    for (int dd = 0; dd < 8; ++dd)                                          \
        KD[dd] = *(const float4*)&kT[((DC) * 8 + dd) * Nn + j0];

#define SCORE_FMA(KD, DC)                                                   \
    _Pragma("unroll")                                                       \
    for (int r = 0; r < ROWS; ++r) {                                        \
        const float4 qa  = *(const float4*)&qs[r][(DC) * 8];                \
        const float4 qb2 = *(const float4*)&qs[r][(DC) * 8 + 4];            \
        const float4* kd = KD;                                              \
        f32x2 a01 = acc01[r], a23 = acc23[r];                               \
        PKSTEP(qa.x, 0) PKSTEP(qa.y, 1) PKSTEP(qa.z, 2) PKSTEP(qa.w, 3)     \
        PKSTEP(qb2.x, 4) PKSTEP(qb2.y, 5) PKSTEP(qb2.z, 6) PKSTEP(qb2.w, 7) \
        acc01[r] = a01; acc23[r] = a23;                                     \
    }

// ---------- sparse top-32 attention (R16-best: ROWS=8, pipelined score) ----------
__global__ __launch_bounds__(512, 4) void attn_sparse(
    const float* __restrict__ Qb, const float* __restrict__ kTb,
    const float* __restrict__ Vx, const float* __restrict__ memk,
    const float* __restrict__ scale, float* __restrict__ attn_out)
{
    __shared__ __align__(16) unsigned int S[ROWS][SROW];   // sortable keys, 66 KB
    __shared__ __align__(16) float qs[ROWS][HDd];          // 1 KB
    __shared__ __align__(16) u64 ulist64[ROWS][64];        // 4 KB  (u<<32 | j)
    __shared__ __align__(16) u64 wj_list[ROWS][64];        // 4 KB  (j<<32 | w bits)

    const int tid    = threadIdx.x;                   // 0..511
    const int ntiles = Nn / ROWS;                     // 256
    const int tile   = blockIdx.x % ntiles;
    const int h      = (blockIdx.x / ntiles) % Hh;
    const int b      = blockIdx.x / (ntiles * Hh);
    const int n0     = tile * ROWS;
    const float sc   = scale[h] * 0.17677669529663688f;

    if (tid < ROWS * HDd) {   // load q tile: 256 threads
        const int r = tid >> 5, d2 = tid & 31;
        qs[r][d2] = Qb[(size_t)(b * Nn + n0 + r) * 256 + h * HDd + d2];
    }
    __syncthreads();

    const float* kT = kTb + (size_t)(b * Hh + h) * (HDd * Nn);   // [32][2048]

    // ---- score phase: keys 0..2047, 512 threads x 4 keys, 2-deep pipeline ----
    {
        const int j0 = tid * 4;
        f32x2 acc01[ROWS], acc23[ROWS];
#pragma unroll
        for (int r = 0; r < ROWS; ++r) { acc01[r] = (f32x2){0.f, 0.f}; acc23[r] = (f32x2){0.f, 0.f}; }
        float4 kdA[8], kdB[8];
        SCORE_LD(kdA, 0)
        SCORE_LD(kdB, 1)
        SCORE_FMA(kdA, 0)
        SCORE_LD(kdA, 2)
        SCORE_FMA(kdB, 1)
        SCORE_LD(kdB, 3)
        SCORE_FMA(kdA, 2)
        SCORE_FMA(kdB, 3)
#pragma unroll
        for (int r = 0; r < ROWS; ++r) {
            const float af[4] = {acc01[r].x, acc01[r].y, acc23[r].x, acc23[r].y};
            uint4 o;
            unsigned int* op = (unsigned int*)&o;
#pragma unroll
            for (int kk = 0; kk < 4; ++kk) {
                float s = af[kk] * sc;
                if (j0 + kk == n0 + r) s = -FLT_MAX;      // diag mask
                op[kk] = f2key(s);
            }
            *(uint4*)&S[r][j0] = o;
        }
    }
    // ---- mem keys 2048..2051: 32 threads (row r, key m), d ascending chain ----
    if (tid < 32) {
        const int r = tid >> 2, m = tid & 3;
        const float* kp = memk + (size_t)(h * Mm + m) * HDd;
        float acc = 0.f;
#pragma unroll
        for (int dcc = 0; dcc < 8; ++dcc) {
            const float4 qv = *(const float4*)&qs[r][dcc * 4];
            const float4 kv = *(const float4*)&kp[dcc * 4];
            acc = fmaf(qv.x, kv.x, acc);
            acc = fmaf(qv.y, kv.y, acc);
            acc = fmaf(qv.z, kv.z, acc);
            acc = fmaf(qv.w, kv.w, acc);
        }
        S[r][2048 + m] = f2key(acc * sc);
    } else {
        // pads 2052..2111: 8 rows x 60 slots = 480 writes by threads 32..511
        const int t2 = tid - 32;
        const int r = t2 / 60, p = t2 % 60;
        S[r][2052 + p] = 0x00800000u;   // f2key(-FLT_MAX)
    }
    __syncthreads();

    // ---- phase 2: one row per wave; keys cached in registers ----
    const int wave = tid >> 6, lane = tid & 63;
    const int half = lane >> 5, d = lane & 31;
    const int n = n0 + wave;

    unsigned int uv[33];
    unsigned int mx = 0u;
    {
        const unsigned int* Srow = &S[wave][lane];
#pragma unroll
        for (int i = 0; i < 33; ++i) {
            uv[i] = Srow[i * 64];
            mx = uv[i] > mx ? uv[i] : mx;
        }
    }
    // slot (i, lane) holds key index j = i*64 + lane.

    auto bitonic = [&](unsigned int vv) -> unsigned int {
#pragma unroll
        for (int kk = 2; kk <= 64; kk <<= 1)
#pragma unroll
            for (int jj = kk >> 1; jj > 0; jj >>= 1) {
                const unsigned int o = (unsigned int)__shfl_xor((int)vv, jj);
                const unsigned int mn = vv < o ? vv : o;
                const unsigned int mxv = vv < o ? o : vv;
                const bool up   = ((lane & kk) == 0);
                const bool lowr = ((lane & jj) == 0);
                vv = (lowr == up) ? mn : mxv;
            }
        return vv;   // ascending: lane 63 = max, lane 32 = 32nd largest
    };
    auto countge = [&](unsigned int tt) -> int {
        int gg = 0;
#pragma unroll
        for (int i = 0; i < 33; ++i) gg += (int)__popcll(__ballot(uv[i] >= tt));
        return gg;   // wave-uniform
    };
    auto compact = [&](unsigned int tt) -> int {
        int bs = 0;
#pragma unroll
        for (int i = 0; i < 33; ++i) {
            const bool p = (uv[i] >= tt);
            const unsigned long long mk = __ballot(p);
            if (p) {
                const int pos = bs + (int)__popcll(mk & ((1ull << lane) - 1ull));
                if (pos < 64)
                    ulist64[wave][pos] = ((u64)uv[i] << 32) | (unsigned int)(i * 64 + lane);
            }
            bs += (int)__popcll(mk);
        }
        return bs;   // wave-uniform total count(>= tt)
    };

    // threshold from lane-max sort: L32 = 32nd-largest lane-max.
    const unsigned int vs1 = bitonic(mx);
    const unsigned int Lmax = (unsigned int)__shfl((int)vs1, 63);   // global max key
    unsigned int t = (unsigned int)__shfl((int)vs1, 32);

    // compact immediately; base IS count(>=t)
    ulist64[wave][lane] = 0ull;
    __asm__ __volatile__("s_waitcnt lgkmcnt(0)" ::: "memory");
    int base = compact(t);
    bool exact = true;
    if (base > 64) {                   // rare: refine with uint bisection
        unsigned int blo = t, bhi = Lmax + 1;   // count(>=blo)>64, count(>=bhi)==0
        int found = 0;
#pragma unroll 1
        for (int it = 0; it < 33; ++it) {
            if (bhi - blo <= 1u) break;
            const unsigned int tm = blo + ((bhi - blo) >> 1);
            const int gm = countge(tm);
            if (gm > 64) blo = tm;
            else if (gm < 32) bhi = tm;
            else { t = tm; found = 1; break; }
        }
        if (!found) t = blo;
        ulist64[wave][lane] = 0ull;
        __asm__ __volatile__("s_waitcnt lgkmcnt(0)" ::: "memory");
        base = compact(t);
        exact = (base <= 64);
    }
    const int C2 = base < 64 ? base : 64;
    __asm__ __volatile__("s_waitcnt lgkmcnt(0)" ::: "memory");
    const u64 pk = ulist64[wave][lane];
    const unsigned int ue = (unsigned int)(pk >> 32);
    const int je = (int)(unsigned int)pk;

    // exact 32nd largest from candidate sort (zeros pad the bottom)
    const unsigned int vs2 = bitonic(ue);
    unsigned int vkkey = (unsigned int)__shfl((int)vs2, 32);
    const unsigned int v31u = (unsigned int)__shfl((int)vs2, 31);
    if (!exact) vkkey = t;

    // ---- boundary analysis from sort byproducts ----
    const bool tie_span = (v31u == vkkey);       // 33rd largest == vk  <=> ties span
    float snx = -3.0e38f;
    if (exact && !tie_span) {
        if (C2 == 32) {       // 33rd largest not in candidate set: sweep for it
            unsigned int unx = 0u;
#pragma unroll
            for (int i = 0; i < 33; ++i) {
                const unsigned int u = uv[i];
                if (u < vkkey && u > unx) unx = u;
            }
#pragma unroll
            for (int o = 32; o > 0; o >>= 1) {
                const unsigned int ou = (unsigned int)__shfl_xor((int)unx, o);
                if (ou > unx) unx = ou;
            }
            snx = key2f(unx);
        } else {
            snx = key2f(v31u);                   // 33rd largest, < vk
        }
    }
    const float svk  = key2f(vkkey);
    const float gapv = svk - snx;
    const float lam  = (exact && !tie_span && gapv > 0.f && gapv <= 4.0e-6f) ? 0.13f : 0.f;

    // softmax weights over kept entries (u >= vkkey); prefilled tail has u=0 -> w=0
    const float mval = key2f(Lmax);
    const float we = (ue >= vkkey) ? __expf(key2f(ue) - mval) : 0.f;
    // half-split layout: evens at 0..31, odds at 32..63
    wj_list[wave][(lane & 1) * 32 + (lane >> 1)] =
        ((u64)(unsigned int)je << 32) | (u64)__float_as_uint(we);
    float Z = we;
#pragma unroll
    for (int o = 32; o > 0; o >>= 1) Z += __shfl_xor(Z, o);
    __asm__ __volatile__("s_waitcnt lgkmcnt(0)" ::: "memory");

    // sparse PV: 8 entries per group; half0 even entries, half1 odd. fma order
    // is program order (e ascending) -> bit-identical; loads pipeline across
    // groups (unroll 2) with 32-bit offsets off a uniform base.
    const float* Vbh = Vx + (size_t)b * (NVROW * 256) + h * HDd;
    float outv = 0.f;
#pragma unroll 2
    for (int e0 = 0; e0 < C2; e0 += 8) {
        const int p0 = (e0 >> 1) + half * 32;
        const ulonglong2 wa = *(const ulonglong2*)&wj_list[wave][p0];
        const ulonglong2 wb = *(const ulonglong2*)&wj_list[wave][p0 + 2];
        float w[4]; unsigned int q[4];
        w[0] = __uint_as_float((unsigned int)wa.x); q[0] = (unsigned int)(wa.x >> 32);
        w[1] = __uint_as_float((unsigned int)wa.y); q[1] = (unsigned int)(wa.y >> 32);
        w[2] = __uint_as_float((unsigned int)wb.x); q[2] = (unsigned int)(wb.x >> 32);
        w[3] = __uint_as_float((unsigned int)wb.y); q[3] = (unsigned int)(wb.y >> 32);
        float vv[4];
#pragma unroll
        for (int u2 = 0; u2 < 4; ++u2)
            vv[u2] = Vbh[q[u2] * 256u + (unsigned int)d];
#pragma unroll
        for (int u2 = 0; u2 < 4; ++u2)
            outv = fmaf(w[u2], vv[u2], outv);
    }
    outv += __shfl_xor(outv, 32);

    float res = outv / Z;
    if (lam > 0.f) {
        // rare hedge: recover indices jd1 (lowest kept) / jnx (highest dropped)
        unsigned int unx2 = 0u; int jnx = 0, jd1 = -1;
#pragma unroll
        for (int i = 0; i < 33; ++i) {
            const unsigned int u = uv[i];
            const int jj2 = i * 64 + lane;
            if (u < vkkey && u > unx2) { unx2 = u; jnx = jj2; }
            if (u == vkkey && jj2 > jd1) jd1 = jj2;
        }
#pragma unroll
        for (int o = 32; o > 0; o >>= 1) {
            const unsigned int ou = (unsigned int)__shfl_xor((int)unx2, o);
            const int oj = __shfl_xor(jnx, o);
            if (ou > unx2 || (ou == unx2 && oj > jnx)) { unx2 = ou; jnx = oj; }
            const int od = __shfl_xor(jd1, o);
            if (od > jd1) jd1 = od;
        }
        const float wd = __expf(svk - mval);
        const float wn = __expf(key2f(unx2) - mval);
        const float* vp1 = Vbh + (size_t)jd1 * 256;
        const float* vpn = Vbh + (size_t)jnx * 256;
        const float ZB = Z - wd + wn;
        const float oB = (outv - wd * vp1[d] + wn * vpn[d]) / ZB;
        res = (1.f - lam) * res + lam * oB;
    }
    if (half == 0)
        attn_out[(size_t)(b * Nn + n) * 256 + h * HDd + d] = res;
}

extern "C" void kernel_launch(void* const* d_in, const int* in_sizes, int n_in,
                              void* d_out, int out_size, void* d_ws, size_t ws_size,
                              hipStream_t stream) {
    const float* x      = (const float*)d_in[0];
    const float* w_qkv  = (const float*)d_in[1];
    const float* b_qkv  = (const float*)d_in[2];
    const float* w_proj = (const float*)d_in[3];
    const float* b_proj = (const float*)d_in[4];
    const float* scale  = (const float*)d_in[5];
    const float* mem_k  = (const float*)d_in[6];
    const float* mem_v  = (const float*)d_in[7];
    float* out = (float*)d_out;

    // workspace: Q/aout 8 MB | kT 8 MB | Vext 8.02 MB  (attn output aliases Qb:
    // each attn block reads exactly the Q slots it later writes -> race-free)
    float* Qb  = (float*)d_ws;
    float* kTb = Qb  + (size_t)Bb * Nn * 256;
    float* Vx  = kTb + (size_t)Bb * Hh * HDd * Nn;

    sgemm_qkv<<<dim3(768 / 64, (Bb * Nn) / 128), 256, 0, stream>>>(
        x, w_qkv, b_qkv, Qb, kTb, Vx, mem_v);

    attn_sparse<<<dim3(Bb * Hh * (Nn / ROWS)), 512, 0, stream>>>(
        Qb, kTb, Vx, mem_k, scale, Qb);

    sgemm_bias<<<dim3(DIMc / 64, (Bb * Nn) / 64), 256, 0, stream>>>(
        Qb, w_proj, b_proj, out, Bb * Nn, DIMc, DIMc);
}